// Round 2
// baseline (1391.904 us; speedup 1.0000x reference)
//
#include <hip/hip_runtime.h>
#include <math.h>
#include <stdint.h>

// Problem constants (B,H,W,K,J) = (8,256,256,100,17)
#define HW    65536
#define BATCH 8
#define NJ    17
#define TOPK  100
#define NCH   144   // 8 hm channels + 8*17 hm_hp channels

// d_out float offsets (concatenated outputs, all f32)
#define OFF_HM   0ull
#define OFF_HMHP 20447232ull
#define OFF_DET  30408704ull   // 8*100*40 = 32000 floats

__device__ __forceinline__ float sigmoidf_(float x) {
    return 1.0f / (1.0f + expf(-x));
}

// ---------------------------------------------------------------------------
// Kernel A: elementwise — sigmoid(hm), copy wh, copy hps, copy reg,
// sigmoid(hm_hp), copy hp_offset. One float4 per thread.
// ---------------------------------------------------------------------------
__global__ __launch_bounds__(256) void ew_kernel(
    const float4* __restrict__ in0, const float4* __restrict__ in1,
    const float4* __restrict__ in2, const float4* __restrict__ in3,
    const float4* __restrict__ in4, const float4* __restrict__ in5,
    float4* __restrict__ out)
{
    const int a0 = 131072, a1 = 393216, a2 = 4849664, a3 = 5111808,
              a4 = 7340032, a5 = 7602176;
    int i = blockIdx.x * 256 + threadIdx.x;
    if (i >= a5) return;
    float4 v;
    if (i < a0) {
        v = in0[i];
        v.x = sigmoidf_(v.x); v.y = sigmoidf_(v.y);
        v.z = sigmoidf_(v.z); v.w = sigmoidf_(v.w);
    } else if (i < a1) {
        v = in1[i - a0];
    } else if (i < a2) {
        v = in2[i - a1];
    } else if (i < a3) {
        v = in3[i - a2];
    } else if (i < a4) {
        v = in4[i - a3];
        v.x = sigmoidf_(v.x); v.y = sigmoidf_(v.y);
        v.z = sigmoidf_(v.z); v.w = sigmoidf_(v.w);
    } else {
        v = in5[i - a4];
    }
    out[i] = v;
}

// ---------------------------------------------------------------------------
// NMS'd score at pixel e of a sigmoid map (value if center >= 3x3 max, else 0)
// ---------------------------------------------------------------------------
__device__ __forceinline__ float nms_score(const float* __restrict__ sig, int e) {
    float ce = sig[e];
    int y = e >> 8, x = e & 255;
    bool xm = x > 0, xp = x < 255;
    float m = -INFINITY;
    if (y > 0) {
        if (xm) m = fmaxf(m, sig[e - 257]);
        m = fmaxf(m, sig[e - 256]);
        if (xp) m = fmaxf(m, sig[e - 255]);
    }
    if (xm) m = fmaxf(m, sig[e - 1]);
    if (xp) m = fmaxf(m, sig[e + 1]);
    if (y < 255) {
        if (xm) m = fmaxf(m, sig[e + 255]);
        m = fmaxf(m, sig[e + 256]);
        if (xp) m = fmaxf(m, sig[e + 257]);
    }
    return (ce >= m) ? ce : 0.0f;
}

// ---------------------------------------------------------------------------
// Kernel B: fused NMS + compaction. For each pixel of each channel, compute
// the NMS'd score from the sigmoid maps (in d_out, L2-warm); positives are
// appended as 48-bit sortable keys to a per-channel list via wave-aggregated
// global atomics. key = (sortable_float << 16) | (65535 - pix): descending
// value, ties -> lower pix (matches jax.lax.top_k).
// ---------------------------------------------------------------------------
__global__ __launch_bounds__(256) void nms_compact_kernel(
    const float* __restrict__ sig_hm, const float* __restrict__ sig_hmhp,
    unsigned long long* __restrict__ lists, unsigned int* __restrict__ counts,
    int cap)
{
    int c = blockIdx.y;
    int pix = blockIdx.x * 256 + threadIdx.x;
    const float* sig = (c < 8) ? (sig_hm + (size_t)c * HW)
                               : (sig_hmhp + (size_t)(c - 8) * HW);
    float v = nms_score(sig, pix);
    bool pred = v > 0.0f;

    unsigned long long mask = __ballot(pred);
    if (mask) {
        int lane = threadIdx.x & 63;
        int leader = __ffsll((long long)mask) - 1;
        unsigned int base = 0;
        if (lane == leader)
            base = atomicAdd(&counts[c], (unsigned int)__popcll(mask));
        base = (unsigned int)__shfl((int)base, leader);
        if (pred) {
            unsigned int off = (unsigned int)__popcll(mask & ((1ULL << lane) - 1ULL));
            unsigned int pos = base + off;
            if (pos < (unsigned int)cap) {
                unsigned int su = __float_as_uint(v) | 0x80000000u;
                unsigned long long key =
                    ((unsigned long long)su << 16) | (unsigned long long)(65535 - pix);
                lists[(size_t)c * cap + pos] = key;
            }
        }
    }
}

// ---------------------------------------------------------------------------
// Kernel C: exact top-100 per channel via 48-bit-key radix select over the
// compact candidate list (~7300 keys/channel). Fallback: if the list
// overflowed (count > cap), scan the full channel recomputing NMS scores.
// Then: hm channels (c<8) -> write det bbox/score/cls + stash inds;
//       hm_hp channels   -> apply hp_offset gather + threshold, stash cands.
// ---------------------------------------------------------------------------
__global__ __launch_bounds__(256) void select_kernel(
    const unsigned long long* __restrict__ lists,
    const unsigned int* __restrict__ counts, int cap,
    const float* __restrict__ sig_hm, const float* __restrict__ sig_hmhp,
    const float* __restrict__ reg, const float* __restrict__ wh,
    const float* __restrict__ hpo,
    float* __restrict__ det, int* __restrict__ ind_hm,
    float* __restrict__ cx, float* __restrict__ cy, float* __restrict__ cs)
{
    __shared__ unsigned int hist[4096];
    __shared__ unsigned int chunk[256];
    __shared__ unsigned long long keys[128];
    __shared__ unsigned long long s_prefix;
    __shared__ int s_krem;
    __shared__ int s_cnt;

    const int c = blockIdx.x;
    const int tid = threadIdx.x;
    const int total = (int)counts[c];
    const bool fb = (total > cap);           // overflow fallback (never on this data)
    const int N = fb ? HW : total;
    const unsigned long long* list = lists + (size_t)c * cap;
    const float* sig = (c < 8) ? (sig_hm + (size_t)c * HW)
                               : (sig_hmhp + (size_t)(c - 8) * HW);

    auto get_key = [&](int i, bool& valid) -> unsigned long long {
        if (!fb) { valid = true; return list[i]; }
        float v = nms_score(sig, i);
        valid = v > 0.0f;
        unsigned int su = __float_as_uint(v) | 0x80000000u;
        return ((unsigned long long)su << 16) | (unsigned long long)(65535 - i);
    };

    if (tid == 0) { s_prefix = 0ULL; s_krem = TOPK; s_cnt = 0; }

    unsigned long long prefix = 0;
    int krem = TOPK;

    for (int pass = 0; pass < 4; ++pass) {
        const int shift = 36 - 12 * pass;
        for (int i = tid; i < 4096; i += 256) hist[i] = 0;
        __syncthreads();
        for (int i = tid; i < N; i += 256) {
            bool valid;
            unsigned long long key = get_key(i, valid);
            if (valid && (key >> (shift + 12)) == prefix)
                atomicAdd(&hist[(unsigned int)(key >> shift) & 0xFFFu], 1u);
        }
        __syncthreads();
        unsigned int csum = 0;
#pragma unroll
        for (int i2 = 0; i2 < 16; ++i2) csum += hist[tid * 16 + i2];
        chunk[tid] = csum;
        __syncthreads();
        if (tid == 0) {
            int cum = 0, sel = 0;
            for (int tc = 255; tc >= 0; --tc) {
                if (cum + (int)chunk[tc] >= krem) {
                    for (int d = tc * 16 + 15;; --d) {
                        cum += (int)hist[d];
                        if (cum >= krem) {
                            sel = d;
                            s_krem = krem - (cum - (int)hist[d]);
                            break;
                        }
                    }
                    break;
                }
                cum += (int)chunk[tc];
            }
            s_prefix = (s_prefix << 12) | (unsigned long long)sel;
        }
        __syncthreads();
        prefix = s_prefix;
        krem = s_krem;
    }

    const unsigned long long T = prefix;  // exact 100th-largest key

    // Collect: exactly 100 distinct keys >= T.
    for (int i = tid; i < N; i += 256) {
        bool valid;
        unsigned long long key = get_key(i, valid);
        if (valid && key >= T) {
            int pos = atomicAdd(&s_cnt, 1);
            if (pos < 128) keys[pos] = key;
        }
    }
    __syncthreads();
    int cnt = s_cnt;
    if (cnt > 128) cnt = 128;
    if (tid < 128 && tid >= cnt) keys[tid] = 0ULL;

    // Bitonic sort 128 keys descending.
    for (int ksz = 2; ksz <= 128; ksz <<= 1) {
        for (int jj = ksz >> 1; jj > 0; jj >>= 1) {
            __syncthreads();
            if (tid < 128) {
                int ixj = tid ^ jj;
                if (ixj > tid) {
                    unsigned long long a = keys[tid], b2 = keys[ixj];
                    bool up = ((tid & ksz) == 0);
                    if (up ? (a < b2) : (a > b2)) {
                        keys[tid] = b2;
                        keys[ixj] = a;
                    }
                }
            }
        }
    }
    __syncthreads();

    if (tid < TOPK) {
        unsigned long long key = keys[tid];
        float val = __uint_as_float((unsigned int)(key >> 16) & 0x7FFFFFFFu);
        int pix = 65535 - (int)(key & 0xFFFFull);
        if (c < 8) {
            int b = c;
            ind_hm[b * TOPK + tid] = pix;
            float xs0 = (float)(pix & 255), ys0 = (float)(pix >> 8);
            float r0 = reg[((size_t)b * 2 + 0) * HW + pix];
            float r1 = reg[((size_t)b * 2 + 1) * HW + pix];
            float w0 = wh[((size_t)b * 2 + 0) * HW + pix];
            float w1 = wh[((size_t)b * 2 + 1) * HW + pix];
            float xs = xs0 + r0, ys = ys0 + r1;
            float* row = det + ((size_t)b * TOPK + tid) * 40;
            row[0] = xs - w0 * 0.5f;
            row[1] = ys - w1 * 0.5f;
            row[2] = xs + w0 * 0.5f;
            row[3] = ys + w1 * 0.5f;
            row[4] = val;
            row[39] = 0.0f;   // cls (C=1 -> always 0)
        } else {
            int cc = c - 8, b = cc / NJ, j = cc % NJ;
            float xs = (float)(pix & 255), ys = (float)(pix >> 8);
            float o0 = hpo[((size_t)b * 2 + 0) * HW + pix];
            float o1 = hpo[((size_t)b * 2 + 1) * HW + pix];
            bool m = val > 0.1f;
            int idx = (b * NJ + j) * TOPK + tid;
            cs[idx] = m ? val : -1.0f;
            cx[idx] = m ? (xs + o0) : -10000.0f;
            cy[idx] = m ? (ys + o1) : -10000.0f;
        }
    }
}

// ---------------------------------------------------------------------------
// Kernel D: per (b,j) block — for each detection k: gather kp regression,
// nearest hm_hp candidate (strict-< keeps first index, matching argmin),
// bad-check against bbox, write kps to detection rows.
// ---------------------------------------------------------------------------
__global__ __launch_bounds__(128) void assign_kernel(
    const float* __restrict__ hps, const int* __restrict__ ind_hm,
    const float* __restrict__ cx, const float* __restrict__ cy,
    const float* __restrict__ cs, float* __restrict__ det)
{
    __shared__ float sx[TOPK], sy[TOPK], ss[TOPK];
    __shared__ float sl[TOPK], st[TOPK], sr[TOPK], sb[TOPK];
    __shared__ float x0[TOPK], y0[TOPK];
    __shared__ int sind[TOPK];

    int b = blockIdx.x / NJ, j = blockIdx.x % NJ;
    int k = threadIdx.x;
    if (k < TOPK) {
        int base = (b * NJ + j) * TOPK + k;
        sx[k] = cx[base]; sy[k] = cy[base]; ss[k] = cs[base];
        const float* row = det + ((size_t)b * TOPK + k) * 40;
        sl[k] = row[0]; st[k] = row[1]; sr[k] = row[2]; sb[k] = row[3];
        int ind = ind_hm[b * TOPK + k];
        sind[k] = ind;
        x0[k] = (float)(ind & 255);
        y0[k] = (float)(ind >> 8);
    }
    __syncthreads();
    if (k < TOPK) {
        int ind = sind[k];
        float kx = hps[((size_t)b * 34 + 2 * j + 0) * HW + ind] + x0[k];
        float ky = hps[((size_t)b * 34 + 2 * j + 1) * HW + ind] + y0[k];
        float best = INFINITY;
        int bi = 0;
        for (int cand = 0; cand < TOPK; ++cand) {
            float dx = kx - sx[cand], dy = ky - sy[cand];
            float d = sqrtf(dx * dx + dy * dy);
            if (d < best) { best = d; bi = cand; }
        }
        float hx = sx[bi], hy = sy[bi], hs = ss[bi];
        float w = sr[k] - sl[k], h = sb[k] - st[k];
        bool bad = (hx < sl[k]) || (hx > sr[k]) || (hy < st[k]) || (hy > sb[k]) ||
                   (hs < 0.1f) || (best > fmaxf(h, w) * 0.3f);
        float ox = bad ? kx : hx;
        float oy = bad ? ky : hy;
        float* orow = det + ((size_t)b * TOPK + k) * 40;
        orow[5 + 2 * j] = ox;
        orow[6 + 2 * j] = oy;
    }
}

// ---------------------------------------------------------------------------
extern "C" void kernel_launch(void* const* d_in, const int* in_sizes, int n_in,
                              void* d_out, int out_size, void* d_ws, size_t ws_size,
                              hipStream_t stream) {
    const float* hm    = (const float*)d_in[0];
    const float* wh    = (const float*)d_in[1];
    const float* hps   = (const float*)d_in[2];
    const float* reg   = (const float*)d_in[3];
    const float* hm_hp = (const float*)d_in[4];
    const float* hpo   = (const float*)d_in[5];
    float* out = (float*)d_out;

    // Workspace layout:
    //   counts : u32 [144]        @ 0
    //   ind_hm : int [800]        @ 1024
    //   cx     : f32 [8*17*100]   @ 8192
    //   cy     : f32 [8*17*100]   @ 65536
    //   cs     : f32 [8*17*100]   @ 131072
    //   lists  : u64 [144*cap]    @ 262144
    char* ws = (char*)d_ws;
    unsigned int* counts = (unsigned int*)ws;
    int*   ind_hm = (int*)(ws + 1024);
    float* cx = (float*)(ws + 8192);
    float* cy = (float*)(ws + 65536);
    float* cs = (float*)(ws + 131072);
    unsigned long long* lists = (unsigned long long*)(ws + 262144);
    long long avail = (long long)ws_size - 262144;
    int cap = 0;
    if (avail > 0) {
        long long c = avail / ((long long)NCH * 8);
        cap = (c > 16384) ? 16384 : (int)c;
    }

    hipMemsetAsync(counts, 0, NCH * sizeof(unsigned int), stream);

    ew_kernel<<<29696, 256, 0, stream>>>(
        (const float4*)hm, (const float4*)wh, (const float4*)hps,
        (const float4*)reg, (const float4*)hm_hp, (const float4*)hpo,
        (float4*)out);

    const float* sig_hm   = out + OFF_HM;
    const float* sig_hmhp = out + OFF_HMHP;
    float* det = out + OFF_DET;

    nms_compact_kernel<<<dim3(HW / 256, NCH), 256, 0, stream>>>(
        sig_hm, sig_hmhp, lists, counts, cap);

    select_kernel<<<NCH, 256, 0, stream>>>(
        lists, counts, cap, sig_hm, sig_hmhp, reg, wh, hpo,
        det, ind_hm, cx, cy, cs);

    assign_kernel<<<BATCH * NJ, 128, 0, stream>>>(hps, ind_hm, cx, cy, cs, det);
}

// Round 3
// 359.271 us; speedup vs baseline: 3.8742x; 3.8742x over previous
//
#include <hip/hip_runtime.h>
#include <math.h>
#include <stdint.h>

// Problem constants (B,H,W,K,J) = (8,256,256,100,17)
#define HW    65536
#define BATCH 8
#define NJ    17
#define TOPK  100
#define NCH   144   // 8 hm channels + 8*17 hm_hp channels
#define CSTRIDE 16 // counts padded: one counter per 64B cacheline

// d_out float offsets (concatenated outputs, all f32)
#define OFF_HM   0ull
#define OFF_HMHP 20447232ull
#define OFF_DET  30408704ull   // 8*100*40 = 32000 floats

__device__ __forceinline__ float sigmoidf_(float x) {
    return 1.0f / (1.0f + expf(-x));
}

// ---------------------------------------------------------------------------
// Kernel A: elementwise — sigmoid(hm), copy wh, copy hps, copy reg,
// sigmoid(hm_hp), copy hp_offset. One float4 per thread.
// ---------------------------------------------------------------------------
__global__ __launch_bounds__(256) void ew_kernel(
    const float4* __restrict__ in0, const float4* __restrict__ in1,
    const float4* __restrict__ in2, const float4* __restrict__ in3,
    const float4* __restrict__ in4, const float4* __restrict__ in5,
    float4* __restrict__ out)
{
    const int a0 = 131072, a1 = 393216, a2 = 4849664, a3 = 5111808,
              a4 = 7340032, a5 = 7602176;
    int i = blockIdx.x * 256 + threadIdx.x;
    if (i >= a5) return;
    float4 v;
    if (i < a0) {
        v = in0[i];
        v.x = sigmoidf_(v.x); v.y = sigmoidf_(v.y);
        v.z = sigmoidf_(v.z); v.w = sigmoidf_(v.w);
    } else if (i < a1) {
        v = in1[i - a0];
    } else if (i < a2) {
        v = in2[i - a1];
    } else if (i < a3) {
        v = in3[i - a2];
    } else if (i < a4) {
        v = in4[i - a3];
        v.x = sigmoidf_(v.x); v.y = sigmoidf_(v.y);
        v.z = sigmoidf_(v.z); v.w = sigmoidf_(v.w);
    } else {
        v = in5[i - a4];
    }
    out[i] = v;
}

// ---------------------------------------------------------------------------
// NMS'd score at pixel e of a sigmoid map (value if center >= 3x3 max, else 0)
// ---------------------------------------------------------------------------
__device__ __forceinline__ float nms_score(const float* __restrict__ sig, int e) {
    float ce = sig[e];
    int y = e >> 8, x = e & 255;
    bool xm = x > 0, xp = x < 255;
    float m = -INFINITY;
    if (y > 0) {
        if (xm) m = fmaxf(m, sig[e - 257]);
        m = fmaxf(m, sig[e - 256]);
        if (xp) m = fmaxf(m, sig[e - 255]);
    }
    if (xm) m = fmaxf(m, sig[e - 1]);
    if (xp) m = fmaxf(m, sig[e + 1]);
    if (y < 255) {
        if (xm) m = fmaxf(m, sig[e + 255]);
        m = fmaxf(m, sig[e + 256]);
        if (xp) m = fmaxf(m, sig[e + 257]);
    }
    return (ce >= m) ? ce : 0.0f;
}

// ---------------------------------------------------------------------------
// Kernel B: fused NMS + compaction, block-aggregated.
// Each block owns a 4096-pixel slice of one channel. Scores kept in 16
// registers; per-thread positive counts scanned in LDS; ONE global atomic
// per block (counters padded to a cacheline each) fetches the base; threads
// then write their keys at deterministic offsets.
// key = (sortable_float << 16) | (65535 - pix): descending value, ties ->
// lower pix (matches jax.lax.top_k).
// ---------------------------------------------------------------------------
__global__ __launch_bounds__(256) void nms_compact_kernel(
    const float* __restrict__ sig_hm, const float* __restrict__ sig_hmhp,
    unsigned long long* __restrict__ lists, unsigned int* __restrict__ counts,
    int cap)
{
    __shared__ unsigned int sA[256], sB[256];
    __shared__ unsigned int s_base;

    const int c = blockIdx.y;
    const int tid = threadIdx.x;
    const int sliceBase = blockIdx.x * 4096;
    const float* sig = (c < 8) ? (sig_hm + (size_t)c * HW)
                               : (sig_hmhp + (size_t)(c - 8) * HW);

    float v[16];
    unsigned int cnt = 0;
#pragma unroll
    for (int it = 0; it < 16; ++it) {
        int pix = sliceBase + it * 256 + tid;
        v[it] = nms_score(sig, pix);
        cnt += (v[it] > 0.0f) ? 1u : 0u;
    }

    // Block-wide inclusive scan of per-thread counts (Hillis-Steele, LDS).
    sA[tid] = cnt;
    __syncthreads();
    unsigned int* src = sA;
    unsigned int* dst = sB;
#pragma unroll
    for (int off = 1; off < 256; off <<= 1) {
        unsigned int x = src[tid];
        if (tid >= off) x += src[tid - off];
        dst[tid] = x;
        __syncthreads();
        unsigned int* t = src; src = dst; dst = t;
    }
    unsigned int incl = src[tid];
    unsigned int prefix = incl - cnt;          // exclusive prefix
    if (tid == 255)
        s_base = atomicAdd(&counts[c * CSTRIDE], incl);
    __syncthreads();
    unsigned int base = s_base;

    unsigned long long* list = lists + (size_t)c * cap;
    unsigned int pos = base + prefix;
#pragma unroll
    for (int it = 0; it < 16; ++it) {
        if (v[it] > 0.0f) {
            if (pos < (unsigned int)cap) {
                int pix = sliceBase + it * 256 + tid;
                unsigned int su = __float_as_uint(v[it]) | 0x80000000u;
                list[pos] = ((unsigned long long)su << 16) |
                            (unsigned long long)(65535 - pix);
            }
            ++pos;
        }
    }
}

// ---------------------------------------------------------------------------
// Kernel C: exact top-100 per channel via 48-bit-key radix select over the
// compact candidate list (~7300 keys/channel). Fallback: if the list
// overflowed (count > cap), scan the full channel recomputing NMS scores.
// Then: hm channels (c<8) -> write det bbox/score/cls + stash inds;
//       hm_hp channels   -> apply hp_offset gather + threshold, stash cands.
// ---------------------------------------------------------------------------
__global__ __launch_bounds__(256) void select_kernel(
    const unsigned long long* __restrict__ lists,
    const unsigned int* __restrict__ counts, int cap,
    const float* __restrict__ sig_hm, const float* __restrict__ sig_hmhp,
    const float* __restrict__ reg, const float* __restrict__ wh,
    const float* __restrict__ hpo,
    float* __restrict__ det, int* __restrict__ ind_hm,
    float* __restrict__ cx, float* __restrict__ cy, float* __restrict__ cs)
{
    __shared__ unsigned int hist[4096];
    __shared__ unsigned int chunk[256];
    __shared__ unsigned long long keys[128];
    __shared__ unsigned long long s_prefix;
    __shared__ int s_krem;
    __shared__ int s_cnt;

    const int c = blockIdx.x;
    const int tid = threadIdx.x;
    const int total = (int)counts[c * CSTRIDE];
    const bool fb = (total > cap);           // overflow fallback (never on this data)
    const int N = fb ? HW : total;
    const unsigned long long* list = lists + (size_t)c * cap;
    const float* sig = (c < 8) ? (sig_hm + (size_t)c * HW)
                               : (sig_hmhp + (size_t)(c - 8) * HW);

    auto get_key = [&](int i, bool& valid) -> unsigned long long {
        if (!fb) { valid = true; return list[i]; }
        float v = nms_score(sig, i);
        valid = v > 0.0f;
        unsigned int su = __float_as_uint(v) | 0x80000000u;
        return ((unsigned long long)su << 16) | (unsigned long long)(65535 - i);
    };

    if (tid == 0) { s_prefix = 0ULL; s_krem = TOPK; s_cnt = 0; }

    unsigned long long prefix = 0;
    int krem = TOPK;

    for (int pass = 0; pass < 4; ++pass) {
        const int shift = 36 - 12 * pass;
        for (int i = tid; i < 4096; i += 256) hist[i] = 0;
        __syncthreads();
        for (int i = tid; i < N; i += 256) {
            bool valid;
            unsigned long long key = get_key(i, valid);
            if (valid && (key >> (shift + 12)) == prefix)
                atomicAdd(&hist[(unsigned int)(key >> shift) & 0xFFFu], 1u);
        }
        __syncthreads();
        unsigned int csum = 0;
#pragma unroll
        for (int i2 = 0; i2 < 16; ++i2) csum += hist[tid * 16 + i2];
        chunk[tid] = csum;
        __syncthreads();
        if (tid == 0) {
            int cum = 0, sel = 0;
            for (int tc = 255; tc >= 0; --tc) {
                if (cum + (int)chunk[tc] >= krem) {
                    for (int d = tc * 16 + 15;; --d) {
                        cum += (int)hist[d];
                        if (cum >= krem) {
                            sel = d;
                            s_krem = krem - (cum - (int)hist[d]);
                            break;
                        }
                    }
                    break;
                }
                cum += (int)chunk[tc];
            }
            s_prefix = (s_prefix << 12) | (unsigned long long)sel;
        }
        __syncthreads();
        prefix = s_prefix;
        krem = s_krem;
    }

    const unsigned long long T = prefix;  // exact 100th-largest key

    // Collect: exactly 100 distinct keys >= T.
    for (int i = tid; i < N; i += 256) {
        bool valid;
        unsigned long long key = get_key(i, valid);
        if (valid && key >= T) {
            int pos = atomicAdd(&s_cnt, 1);
            if (pos < 128) keys[pos] = key;
        }
    }
    __syncthreads();
    int cnt = s_cnt;
    if (cnt > 128) cnt = 128;
    if (tid < 128 && tid >= cnt) keys[tid] = 0ULL;

    // Bitonic sort 128 keys descending.
    for (int ksz = 2; ksz <= 128; ksz <<= 1) {
        for (int jj = ksz >> 1; jj > 0; jj >>= 1) {
            __syncthreads();
            if (tid < 128) {
                int ixj = tid ^ jj;
                if (ixj > tid) {
                    unsigned long long a = keys[tid], b2 = keys[ixj];
                    bool up = ((tid & ksz) == 0);
                    if (up ? (a < b2) : (a > b2)) {
                        keys[tid] = b2;
                        keys[ixj] = a;
                    }
                }
            }
        }
    }
    __syncthreads();

    if (tid < TOPK) {
        unsigned long long key = keys[tid];
        float val = __uint_as_float((unsigned int)(key >> 16) & 0x7FFFFFFFu);
        int pix = 65535 - (int)(key & 0xFFFFull);
        if (c < 8) {
            int b = c;
            ind_hm[b * TOPK + tid] = pix;
            float xs0 = (float)(pix & 255), ys0 = (float)(pix >> 8);
            float r0 = reg[((size_t)b * 2 + 0) * HW + pix];
            float r1 = reg[((size_t)b * 2 + 1) * HW + pix];
            float w0 = wh[((size_t)b * 2 + 0) * HW + pix];
            float w1 = wh[((size_t)b * 2 + 1) * HW + pix];
            float xs = xs0 + r0, ys = ys0 + r1;
            float* row = det + ((size_t)b * TOPK + tid) * 40;
            row[0] = xs - w0 * 0.5f;
            row[1] = ys - w1 * 0.5f;
            row[2] = xs + w0 * 0.5f;
            row[3] = ys + w1 * 0.5f;
            row[4] = val;
            row[39] = 0.0f;   // cls (C=1 -> always 0)
        } else {
            int cc = c - 8, b = cc / NJ, j = cc % NJ;
            float xs = (float)(pix & 255), ys = (float)(pix >> 8);
            float o0 = hpo[((size_t)b * 2 + 0) * HW + pix];
            float o1 = hpo[((size_t)b * 2 + 1) * HW + pix];
            bool m = val > 0.1f;
            int idx = (b * NJ + j) * TOPK + tid;
            cs[idx] = m ? val : -1.0f;
            cx[idx] = m ? (xs + o0) : -10000.0f;
            cy[idx] = m ? (ys + o1) : -10000.0f;
        }
    }
}

// ---------------------------------------------------------------------------
// Kernel D: per (b,j) block — for each detection k: gather kp regression,
// nearest hm_hp candidate (strict-< keeps first index, matching argmin),
// bad-check against bbox, write kps to detection rows.
// ---------------------------------------------------------------------------
__global__ __launch_bounds__(128) void assign_kernel(
    const float* __restrict__ hps, const int* __restrict__ ind_hm,
    const float* __restrict__ cx, const float* __restrict__ cy,
    const float* __restrict__ cs, float* __restrict__ det)
{
    __shared__ float sx[TOPK], sy[TOPK], ss[TOPK];
    __shared__ float sl[TOPK], st[TOPK], sr[TOPK], sb[TOPK];
    __shared__ float x0[TOPK], y0[TOPK];
    __shared__ int sind[TOPK];

    int b = blockIdx.x / NJ, j = blockIdx.x % NJ;
    int k = threadIdx.x;
    if (k < TOPK) {
        int base = (b * NJ + j) * TOPK + k;
        sx[k] = cx[base]; sy[k] = cy[base]; ss[k] = cs[base];
        const float* row = det + ((size_t)b * TOPK + k) * 40;
        sl[k] = row[0]; st[k] = row[1]; sr[k] = row[2]; sb[k] = row[3];
        int ind = ind_hm[b * TOPK + k];
        sind[k] = ind;
        x0[k] = (float)(ind & 255);
        y0[k] = (float)(ind >> 8);
    }
    __syncthreads();
    if (k < TOPK) {
        int ind = sind[k];
        float kx = hps[((size_t)b * 34 + 2 * j + 0) * HW + ind] + x0[k];
        float ky = hps[((size_t)b * 34 + 2 * j + 1) * HW + ind] + y0[k];
        float best = INFINITY;
        int bi = 0;
        for (int cand = 0; cand < TOPK; ++cand) {
            float dx = kx - sx[cand], dy = ky - sy[cand];
            float d = sqrtf(dx * dx + dy * dy);
            if (d < best) { best = d; bi = cand; }
        }
        float hx = sx[bi], hy = sy[bi], hs = ss[bi];
        float w = sr[k] - sl[k], h = sb[k] - st[k];
        bool bad = (hx < sl[k]) || (hx > sr[k]) || (hy < st[k]) || (hy > sb[k]) ||
                   (hs < 0.1f) || (best > fmaxf(h, w) * 0.3f);
        float ox = bad ? kx : hx;
        float oy = bad ? ky : hy;
        float* orow = det + ((size_t)b * TOPK + k) * 40;
        orow[5 + 2 * j] = ox;
        orow[6 + 2 * j] = oy;
    }
}

// ---------------------------------------------------------------------------
extern "C" void kernel_launch(void* const* d_in, const int* in_sizes, int n_in,
                              void* d_out, int out_size, void* d_ws, size_t ws_size,
                              hipStream_t stream) {
    const float* hm    = (const float*)d_in[0];
    const float* wh    = (const float*)d_in[1];
    const float* hps   = (const float*)d_in[2];
    const float* reg   = (const float*)d_in[3];
    const float* hm_hp = (const float*)d_in[4];
    const float* hpo   = (const float*)d_in[5];
    float* out = (float*)d_out;

    // Workspace layout:
    //   counts : u32 [144*16]     @ 0       (padded, 1 counter / cacheline)
    //   ind_hm : int [800]        @ 16384
    //   cx     : f32 [8*17*100]   @ 32768
    //   cy     : f32 [8*17*100]   @ 98304
    //   cs     : f32 [8*17*100]   @ 163840
    //   lists  : u64 [144*cap]    @ 262144
    char* ws = (char*)d_ws;
    unsigned int* counts = (unsigned int*)ws;
    int*   ind_hm = (int*)(ws + 16384);
    float* cx = (float*)(ws + 32768);
    float* cy = (float*)(ws + 98304);
    float* cs = (float*)(ws + 163840);
    unsigned long long* lists = (unsigned long long*)(ws + 262144);
    long long avail = (long long)ws_size - 262144;
    int cap = 0;
    if (avail > 0) {
        long long c = avail / ((long long)NCH * 8);
        cap = (c > 16384) ? 16384 : (int)c;
    }

    hipMemsetAsync(counts, 0, NCH * CSTRIDE * sizeof(unsigned int), stream);

    ew_kernel<<<29696, 256, 0, stream>>>(
        (const float4*)hm, (const float4*)wh, (const float4*)hps,
        (const float4*)reg, (const float4*)hm_hp, (const float4*)hpo,
        (float4*)out);

    const float* sig_hm   = out + OFF_HM;
    const float* sig_hmhp = out + OFF_HMHP;
    float* det = out + OFF_DET;

    nms_compact_kernel<<<dim3(16, NCH), 256, 0, stream>>>(
        sig_hm, sig_hmhp, lists, counts, cap);

    select_kernel<<<NCH, 256, 0, stream>>>(
        lists, counts, cap, sig_hm, sig_hmhp, reg, wh, hpo,
        det, ind_hm, cx, cy, cs);

    assign_kernel<<<BATCH * NJ, 128, 0, stream>>>(hps, ind_hm, cx, cy, cs, det);
}